// Round 10
// baseline (105.974 us; speedup 1.0000x reference)
//
#include <hip/hip_runtime.h>

#define NF 128
#define NBMAX 4096     // max 32-row buckets (N <= 131072)
#define RPB 32         // rows per bucket
#define CAPB 768       // per-bucket edge capacity (Poisson(512) + 11 sigma)
#define CHUNK 8192     // edges per bucketize role-block
#define PREP_THREADS 1024

typedef unsigned int uint;
typedef unsigned short ushort;
typedef unsigned char uchar;
typedef __attribute__((ext_vector_type(8))) short bf16x8;
typedef __attribute__((ext_vector_type(4))) float f32x4;
typedef __attribute__((ext_vector_type(2))) float f32x2;

__device__ inline ushort f32_to_bf16(float f) {
    uint u = __float_as_uint(f);
    return (ushort)((u + 0x7FFFu + ((u >> 16) & 1u)) >> 16);
}

// ---------------- mega-prep: convert x->xq(fp8) || prep_Wfrag || bucketize ------
// Wfrag layout: frag f=(kc*8+nf), lane l, j: Wfrag[f*512 + l*8 + j] =
//   bf16(W[(kc*32+(l>>4)*8+j)*128 + nf*16+(l&15)])
__global__ __launch_bounds__(PREP_THREADS) void prep_kernel(
    const float* __restrict__ x, uchar* __restrict__ xq, int total8,
    const float* __restrict__ W, ushort* __restrict__ Wfrag,
    const int* __restrict__ erow, const int* __restrict__ ecol,
    int* __restrict__ bcur, uint* __restrict__ bbuf, int E, int NB, int CB) {
    __shared__ int pos[NBMAX];
    const int b = blockIdx.x;
    const int tid = threadIdx.x;

    if (b < CB) {
        // ---- convert x (f32) -> xq (fp8 e4m3, RNE via v_cvt_pk_fp8_f32) ----
        int base = b * (PREP_THREADS * 4) + tid;
#pragma unroll
        for (int p = 0; p < 4; ++p) {
            int i = base + p * PREP_THREADS;
            if (i < total8) {
                const float4 a = ((const float4*)x)[i * 2];
                const float4 c = ((const float4*)x)[i * 2 + 1];
                int q0 = __builtin_amdgcn_cvt_pk_fp8_f32(a.x, a.y, 0, false);
                q0 = __builtin_amdgcn_cvt_pk_fp8_f32(a.z, a.w, q0, true);
                int q1 = __builtin_amdgcn_cvt_pk_fp8_f32(c.x, c.y, 0, false);
                q1 = __builtin_amdgcn_cvt_pk_fp8_f32(c.z, c.w, q1, true);
                ((uint2*)xq)[i] = make_uint2((uint)q0, (uint)q1);
            }
        }
    } else if (b == CB) {
        // ---- W -> fragment-ordered bf16 Wfrag ----
        for (int idx = tid; idx < 64 * 64 * 8; idx += PREP_THREADS) {
            int f = idx >> 9, l = (idx >> 3) & 63, j = idx & 7;
            int kc = f >> 3, nf = f & 7;
            int k = kc * 32 + ((l >> 4) << 3) + j;
            int col = nf * 16 + (l & 15);
            Wfrag[idx] = f32_to_bf16(W[(size_t)k * 128 + col]);
        }
    } else {
        // ---- bucketize an 8192-edge chunk into 32-row buckets ----
        const int start = (b - CB - 1) * CHUNK;
        const int end = min(start + CHUNK, E);
        for (int q = tid; q < NB; q += PREP_THREADS) pos[q] = 0;
        __syncthreads();
        for (int i = start + tid; i < end; i += PREP_THREADS) atomicAdd(&pos[erow[i] >> 5], 1);
        __syncthreads();
        for (int q = tid; q < NB; q += PREP_THREADS) {
            int c = pos[q];
            pos[q] = (c > 0) ? atomicAdd(&bcur[q], c) : 0;
        }
        __syncthreads();
        for (int i = start + tid; i < end; i += PREP_THREADS) {
            int r = erow[i], c = ecol[i];
            int bkt = r >> 5;
            int p = atomicAdd(&pos[bkt], 1);
            bbuf[(size_t)bkt * CAPB + p] = ((uint)(r & 31) << 17) | (uint)c;
        }
    }
}

// decode 16 fp8 (uint4) -> f32 accumulate (cvt_pk returns ext-vector: use [i])
#define DECADD(v)                                                            \
    {                                                                        \
        f32x2 t0 = __builtin_amdgcn_cvt_pk_f32_fp8((int)(v).x, false);       \
        f32x2 t1 = __builtin_amdgcn_cvt_pk_f32_fp8((int)(v).x, true);        \
        f32x2 t2 = __builtin_amdgcn_cvt_pk_f32_fp8((int)(v).y, false);       \
        f32x2 t3 = __builtin_amdgcn_cvt_pk_f32_fp8((int)(v).y, true);        \
        f32x2 t4 = __builtin_amdgcn_cvt_pk_f32_fp8((int)(v).z, false);       \
        f32x2 t5 = __builtin_amdgcn_cvt_pk_f32_fp8((int)(v).z, true);        \
        f32x2 t6 = __builtin_amdgcn_cvt_pk_f32_fp8((int)(v).w, false);       \
        f32x2 t7 = __builtin_amdgcn_cvt_pk_f32_fp8((int)(v).w, true);        \
        acc[0] += t0[0];  acc[1] += t0[1];  acc[2] += t1[0];  acc[3] += t1[1];   \
        acc[4] += t2[0];  acc[5] += t2[1];  acc[6] += t3[0];  acc[7] += t3[1];   \
        acc[8] += t4[0];  acc[9] += t4[1];  acc[10] += t5[0]; acc[11] += t5[1];  \
        acc[12] += t6[0]; acc[13] += t6[1]; acc[14] += t7[0]; acc[15] += t7[1];  \
    }

// ---------------- fused: sort + fp8 gather-mean + MFMA GEMM + ReLU --------------
// One block per 32-row bucket (1:1, no half-filter). Gather: 32 units x 8
// lanes, one row per unit, 128B/neighbor (gather stays fp8: its quant noise is
// averaged over ~deg neighbors). GEMM A x-half stays F32->bf16 (R9 lesson:
// fp8 self-features enter W unattenuated -> absmax 0.121 FAIL). The f32 x
// loads are PREFETCHED before the sort so their latency hides there.
__global__ __launch_bounds__(256) void fused_kernel(
    const float* __restrict__ x, const uchar* __restrict__ xq,
    const int* __restrict__ bcur, const uint* __restrict__ bbuf,
    const ushort* __restrict__ Wfrag, float* __restrict__ out, int N) {
    __shared__ int offs[RPB + 1];
    __shared__ int cur[RPB];
    __shared__ int cols[CAPB];
    __shared__ ushort nl[RPB * 256];   // row stride 512B, byte ^= (row&7)<<4 swizzle
    const int b = blockIdx.x;
    const int tid = threadIdx.x;
    const int cnt = min(bcur[b], CAPB);
    const uint* buf = bbuf + (size_t)b * CAPB;

    // ---- GEMM A x-half prefetch (f32 -> bf16 RNE, held in 16 VGPRs) ----
    const int wid = tid >> 6, lane = tid & 63;
    const int lm = lane & 15;
    const int lkb = (lane >> 4) * 8;
    const int mf = wid >> 1, nquad = wid & 1;
    const int lrow = mf * 16 + lm;               // local row 0..31
    int grow = b * RPB + lrow;
    if (grow >= N) grow = N - 1;                 // clamp: values discarded at store
    bf16x8 aRx[4];
#pragma unroll
    for (int kc = 0; kc < 4; ++kc) {
        const float4 u  = *(const float4*)&x[(size_t)grow * NF + kc * 32 + lkb];
        const float4 w4 = *(const float4*)&x[(size_t)grow * NF + kc * 32 + lkb + 4];
        aRx[kc][0] = (short)f32_to_bf16(u.x);  aRx[kc][1] = (short)f32_to_bf16(u.y);
        aRx[kc][2] = (short)f32_to_bf16(u.z);  aRx[kc][3] = (short)f32_to_bf16(u.w);
        aRx[kc][4] = (short)f32_to_bf16(w4.x); aRx[kc][5] = (short)f32_to_bf16(w4.y);
        aRx[kc][6] = (short)f32_to_bf16(w4.z); aRx[kc][7] = (short)f32_to_bf16(w4.w);
    }

    // ---- counting sort of this bucket's edges by local row ----
    if (tid < RPB) cur[tid] = 0;
    __syncthreads();
    for (int i = tid; i < cnt; i += 256) atomicAdd(&cur[buf[i] >> 17], 1);
    __syncthreads();
    if (tid == 0) {
        int run = 0;
        offs[0] = 0;
        for (int r = 0; r < RPB; ++r) { run += cur[r]; offs[r + 1] = min(run, CAPB); }
    }
    __syncthreads();
    if (tid < RPB) cur[tid] = offs[tid];
    __syncthreads();
    for (int i = tid; i < cnt; i += 256) {
        uint v = buf[i];
        int p = atomicAdd(&cur[v >> 17], 1);
        if (p < CAPB) cols[p] = (int)(v & 0x1FFFFu);
    }
    __syncthreads();

    // ---- gather: 32 units x 8 lanes; unit handles exactly one row ----
    {
        const int r = tid >> 3, lane8 = tid & 7;
        const int j0 = offs[r], j1 = offs[r + 1];
        float acc[16];
#pragma unroll
        for (int q = 0; q < 16; ++q) acc[q] = 0.f;
        int j = j0;
        for (; j + 1 < j1; j += 2) {     // 2-way MLP
            int c0 = cols[j], c1 = cols[j + 1];
            uint4 v0 = *(const uint4*)&xq[(size_t)c0 * NF + lane8 * 16];
            uint4 v1 = *(const uint4*)&xq[(size_t)c1 * NF + lane8 * 16];
            DECADD(v0);
            DECADD(v1);
        }
        if (j < j1) {
            uint4 v0 = *(const uint4*)&xq[(size_t)cols[j] * NF + lane8 * 16];
            DECADD(v0);
        }
        float sc = 1.0f / (float)(j1 - j0 + 1);
        bf16x8 t0, t1;
#pragma unroll
        for (int q = 0; q < 8; ++q) t0[q] = (short)f32_to_bf16(acc[q] * sc);
#pragma unroll
        for (int q = 0; q < 8; ++q) t1[q] = (short)f32_to_bf16(acc[8 + q] * sc);
        uint base = (uint)r * 512 + (uint)lane8 * 32;
        uint x16 = (uint)(r & 7) << 4;
        *(bf16x8*)((char*)nl + (base ^ x16)) = t0;
        *(bf16x8*)((char*)nl + ((base + 16) ^ x16)) = t1;
    }
    __syncthreads();

    // ---- GEMM: 4 waves, each 16 rows x 64 cols (mf = wid>>1, col-quad = wid&1) ----
    f32x4 acc[4] = {};
#pragma unroll
    for (int kc = 0; kc < 8; ++kc) {
        bf16x8 aR;
        if (kc < 4) {
            aR = aRx[kc];
        } else {
            uint boff = ((uint)lrow * 512 + (uint)((kc - 4) * 32 + lkb) * 2)
                        ^ ((uint)(lrow & 7) << 4);
            aR = *(const bf16x8*)((const char*)nl + boff);
        }
        const ushort* wf = &Wfrag[(size_t)(kc * 8 + nquad * 4) * 512 + (size_t)lane * 8];
#pragma unroll
        for (int nf = 0; nf < 4; ++nf) {
            bf16x8 bR = *(const bf16x8*)(wf + (size_t)nf * 512);
            acc[nf] = __builtin_amdgcn_mfma_f32_16x16x32_bf16(aR, bR, acc[nf], 0, 0, 0);
        }
    }

    // ---- epilogue: ReLU + store (C layout: col=lane&15, row=(lane>>4)*4+reg) ----
    const int rb = mf * 16 + (lane >> 4) * 4;
#pragma unroll
    for (int j = 0; j < 4; ++j) {
        int row = b * RPB + rb + j;
        if (row < N) {
#pragma unroll
            for (int nf = 0; nf < 4; ++nf)
                out[(size_t)row * NF + (nquad * 4 + nf) * 16 + lm] = fmaxf(acc[nf][j], 0.f);
        }
    }
}

// ---------------- launcher ----------------
extern "C" void kernel_launch(void* const* d_in, const int* in_sizes, int n_in,
                              void* d_out, int out_size, void* d_ws, size_t ws_size,
                              hipStream_t stream) {
    const float* x    = (const float*)d_in[0];
    const int*   erow = (const int*)d_in[1];
    const int*   ecol = (const int*)d_in[2];
    const float* W    = (const float*)d_in[3];
    const int N = in_sizes[0] / NF;
    const int E = in_sizes[1];
    float* out = (float*)d_out;

    const int NB = (N + RPB - 1) / RPB;          // 32-row buckets
    const int total8 = N * NF / 8;
    const int CB = (total8 + PREP_THREADS * 4 - 1) / (PREP_THREADS * 4);
    const int BB = (E + CHUNK - 1) / CHUNK;

    // ws layout: xq[N*NF fp8] | Wfrag[64*512 bf16] | bcur[NBMAX] | bbuf[NB*CAPB] (~22.5 MB)
    char* ws = (char*)d_ws;
    uchar*  xq    = (uchar*)ws;
    ushort* Wfrag = (ushort*)(ws + (size_t)N * NF);
    int*    bcur  = (int*)((char*)Wfrag + 64 * 512 * 2);
    uint*   bbuf  = (uint*)(bcur + NBMAX);

    hipMemsetAsync(bcur, 0, (size_t)NB * sizeof(int), stream);
    prep_kernel<<<CB + 1 + BB, PREP_THREADS, 0, stream>>>(
        x, xq, total8, W, Wfrag, erow, ecol, bcur, bbuf, E, NB, CB);
    fused_kernel<<<NB, 256, 0, stream>>>(x, xq, bcur, bbuf, Wfrag, out, N);
}

// Round 11
// 103.091 us; speedup vs baseline: 1.0280x; 1.0280x over previous
//
#include <hip/hip_runtime.h>

#define NF 128
#define NBMAX 4096     // max 32-row fine buckets (N <= 131072)
#define RPB 32         // rows per fine bucket
#define CAPB 768       // per-fine-bucket edge capacity (Poisson(512) + 11 sigma)
#define SROWS 512      // rows per super-bucket (level-1)
#define SCAP 9856      // per-super capacity (mean 8192 + ~18 sigma)
#define FPS 16         // fine buckets per super
#define CHUNK 8192     // edges per level-1 role-block
#define PREP_THREADS 1024

typedef unsigned int uint;
typedef unsigned short ushort;
typedef unsigned char uchar;
typedef __attribute__((ext_vector_type(8))) short bf16x8;
typedef __attribute__((ext_vector_type(4))) float f32x4;
typedef __attribute__((ext_vector_type(2))) float f32x2;

__device__ inline ushort f32_to_bf16(float f) {
    uint u = __float_as_uint(f);
    return (ushort)((u + 0x7FFFu + ((u >> 16) & 1u)) >> 16);
}

// ---------------- prep1: convert x->xq(fp8) || prep_Wfrag || level-1 super-bin --
// Level-1 bins edges into 512-row SUPER buckets: runs of ~42 edges (~168B)
// -> near-full-line HBM writes (the old 32-row direct binning had ~2.6-edge
// runs = 10B partial-line RMW scatter, ~35us of prep).
// Wfrag layout: frag f=(kc*8+nf), lane l, j: Wfrag[f*512 + l*8 + j] =
//   bf16(W[(kc*32+(l>>4)*8+j)*128 + nf*16+(l&15)])
__global__ __launch_bounds__(PREP_THREADS) void prep_kernel(
    const float* __restrict__ x, uchar* __restrict__ xq, int total8,
    const float* __restrict__ W, ushort* __restrict__ Wfrag,
    const int* __restrict__ erow, const int* __restrict__ ecol,
    int* __restrict__ scur, uint* __restrict__ sbuf, int E, int NS, int CB) {
    __shared__ int pos[256];
    const int b = blockIdx.x;
    const int tid = threadIdx.x;

    if (b < CB) {
        // ---- convert x (f32) -> xq (fp8 e4m3, RNE via v_cvt_pk_fp8_f32) ----
        int base = b * (PREP_THREADS * 4) + tid;
#pragma unroll
        for (int p = 0; p < 4; ++p) {
            int i = base + p * PREP_THREADS;
            if (i < total8) {
                const float4 a = ((const float4*)x)[i * 2];
                const float4 c = ((const float4*)x)[i * 2 + 1];
                int q0 = __builtin_amdgcn_cvt_pk_fp8_f32(a.x, a.y, 0, false);
                q0 = __builtin_amdgcn_cvt_pk_fp8_f32(a.z, a.w, q0, true);
                int q1 = __builtin_amdgcn_cvt_pk_fp8_f32(c.x, c.y, 0, false);
                q1 = __builtin_amdgcn_cvt_pk_fp8_f32(c.z, c.w, q1, true);
                ((uint2*)xq)[i] = make_uint2((uint)q0, (uint)q1);
            }
        }
    } else if (b == CB) {
        // ---- W -> fragment-ordered bf16 Wfrag ----
        for (int idx = tid; idx < 64 * 64 * 8; idx += PREP_THREADS) {
            int f = idx >> 9, l = (idx >> 3) & 63, j = idx & 7;
            int kc = f >> 3, nf = f & 7;
            int k = kc * 32 + ((l >> 4) << 3) + j;
            int col = nf * 16 + (l & 15);
            Wfrag[idx] = f32_to_bf16(W[(size_t)k * 128 + col]);
        }
    } else {
        // ---- level-1: bin an 8192-edge chunk into 512-row super buckets ----
        const int start = (b - CB - 1) * CHUNK;
        const int end = min(start + CHUNK, E);
        for (int q = tid; q < NS; q += PREP_THREADS) pos[q] = 0;
        __syncthreads();
        for (int i = start + tid; i < end; i += PREP_THREADS) atomicAdd(&pos[erow[i] >> 9], 1);
        __syncthreads();
        for (int q = tid; q < NS; q += PREP_THREADS) {
            int c = pos[q];
            pos[q] = (c > 0) ? atomicAdd(&scur[q], c) : 0;
        }
        __syncthreads();
        for (int i = start + tid; i < end; i += PREP_THREADS) {
            int r = erow[i], c = ecol[i];
            int s = r >> 9;
            int p = atomicAdd(&pos[s], 1);
            if (p < SCAP) sbuf[(size_t)s * SCAP + p] = ((uint)(r & 511) << 17) | (uint)c;
        }
    }
}

// ---------------- prep2: super -> fine (16x 32-row) binning, single pass --------
// One block per super. Reads its ~8K-edge segment (coalesced), places each edge
// into its fine bucket in bbuf via LDS slot counters (writes land densely in
// 3KB-max windows -> coalesced at L2). Writes bcur directly (no memset needed).
__global__ __launch_bounds__(PREP_THREADS) void binfine_kernel(
    const uint* __restrict__ sbuf, const int* __restrict__ scur,
    uint* __restrict__ bbuf, int* __restrict__ bcur) {
    __shared__ int lcur[FPS];
    const int s = blockIdx.x;
    const int tid = threadIdx.x;
    const int cnt = min(scur[s], SCAP);
    const uint* sb = sbuf + (size_t)s * SCAP;
    if (tid < FPS) lcur[tid] = 0;
    __syncthreads();
    for (int i = tid; i < cnt; i += PREP_THREADS) {
        uint v = sb[i];
        int f = (int)(v >> 22);                  // (row&511)>>5
        int p = atomicAdd(&lcur[f], 1);
        if (p < CAPB)
            bbuf[(size_t)(s * FPS + f) * CAPB + p] =
                (((v >> 17) & 31u) << 17) | (v & 0x1FFFFu);
    }
    __syncthreads();
    if (tid < FPS) bcur[s * FPS + tid] = min(lcur[tid], CAPB);
}

// decode 16 fp8 (uint4) -> f32 accumulate (cvt_pk returns ext-vector: use [i])
#define DECADD(v)                                                            \
    {                                                                        \
        f32x2 t0 = __builtin_amdgcn_cvt_pk_f32_fp8((int)(v).x, false);       \
        f32x2 t1 = __builtin_amdgcn_cvt_pk_f32_fp8((int)(v).x, true);        \
        f32x2 t2 = __builtin_amdgcn_cvt_pk_f32_fp8((int)(v).y, false);       \
        f32x2 t3 = __builtin_amdgcn_cvt_pk_f32_fp8((int)(v).y, true);        \
        f32x2 t4 = __builtin_amdgcn_cvt_pk_f32_fp8((int)(v).z, false);       \
        f32x2 t5 = __builtin_amdgcn_cvt_pk_f32_fp8((int)(v).z, true);        \
        f32x2 t6 = __builtin_amdgcn_cvt_pk_f32_fp8((int)(v).w, false);       \
        f32x2 t7 = __builtin_amdgcn_cvt_pk_f32_fp8((int)(v).w, true);        \
        ga[0] += t0[0];  ga[1] += t0[1];  ga[2] += t1[0];  ga[3] += t1[1];   \
        ga[4] += t2[0];  ga[5] += t2[1];  ga[6] += t3[0];  ga[7] += t3[1];   \
        ga[8] += t4[0];  ga[9] += t4[1];  ga[10] += t5[0]; ga[11] += t5[1];  \
        ga[12] += t6[0]; ga[13] += t6[1]; ga[14] += t7[0]; ga[15] += t7[1];  \
    }

// ---------------- fused: sort + fp8 gather-mean + MFMA GEMM + ReLU --------------
// One block per 32-row fine bucket. Gather: 32 units x 8 lanes, 128B/neighbor
// fp8 (quant noise averaged over ~deg). GEMM A x-half: f32 x -> bf16 RNE
// (prefetched pre-sort), and its 16 MFMAs are HOISTED before the gather so
// only the neigh-half GEMM remains on the post-gather critical path.
__global__ __launch_bounds__(256) void fused_kernel(
    const float* __restrict__ x, const uchar* __restrict__ xq,
    const int* __restrict__ bcur, const uint* __restrict__ bbuf,
    const ushort* __restrict__ Wfrag, float* __restrict__ out, int N) {
    __shared__ int offs[RPB + 1];
    __shared__ int cur[RPB];
    __shared__ int cols[CAPB];
    __shared__ ushort nl[RPB * 256];   // row stride 512B, byte ^= (row&7)<<4 swizzle
    const int b = blockIdx.x;
    const int tid = threadIdx.x;
    const int cnt = min(bcur[b], CAPB);
    const uint* buf = bbuf + (size_t)b * CAPB;

    // ---- GEMM A x-half prefetch (f32 -> bf16 RNE, 16 VGPRs) ----
    const int wid = tid >> 6, lane = tid & 63;
    const int lm = lane & 15;
    const int lkb = (lane >> 4) * 8;
    const int mf = wid >> 1, nquad = wid & 1;
    const int lrow = mf * 16 + lm;               // local row 0..31
    int grow = b * RPB + lrow;
    if (grow >= N) grow = N - 1;                 // clamp: values discarded at store
    bf16x8 aRx[4];
#pragma unroll
    for (int kc = 0; kc < 4; ++kc) {
        const float4 u  = *(const float4*)&x[(size_t)grow * NF + kc * 32 + lkb];
        const float4 w4 = *(const float4*)&x[(size_t)grow * NF + kc * 32 + lkb + 4];
        aRx[kc][0] = (short)f32_to_bf16(u.x);  aRx[kc][1] = (short)f32_to_bf16(u.y);
        aRx[kc][2] = (short)f32_to_bf16(u.z);  aRx[kc][3] = (short)f32_to_bf16(u.w);
        aRx[kc][4] = (short)f32_to_bf16(w4.x); aRx[kc][5] = (short)f32_to_bf16(w4.y);
        aRx[kc][6] = (short)f32_to_bf16(w4.z); aRx[kc][7] = (short)f32_to_bf16(w4.w);
    }

    // ---- counting sort of this bucket's edges by local row ----
    if (tid < RPB) cur[tid] = 0;
    __syncthreads();
    for (int i = tid; i < cnt; i += 256) atomicAdd(&cur[buf[i] >> 17], 1);
    __syncthreads();
    if (tid == 0) {
        int run = 0;
        offs[0] = 0;
        for (int r = 0; r < RPB; ++r) { run += cur[r]; offs[r + 1] = min(run, CAPB); }
    }
    __syncthreads();
    if (tid < RPB) cur[tid] = offs[tid];
    __syncthreads();
    for (int i = tid; i < cnt; i += 256) {
        uint v = buf[i];
        int p = atomicAdd(&cur[v >> 17], 1);
        if (p < CAPB) cols[p] = (int)(v & 0x1FFFFu);
    }

    // ---- hoisted x-half GEMM (no LDS dependency; overlaps sort/gather waits) ----
    f32x4 accG[4] = {};
#pragma unroll
    for (int kc = 0; kc < 4; ++kc) {
        const ushort* wf = &Wfrag[(size_t)(kc * 8 + nquad * 4) * 512 + (size_t)lane * 8];
#pragma unroll
        for (int nf = 0; nf < 4; ++nf) {
            bf16x8 bR = *(const bf16x8*)(wf + (size_t)nf * 512);
            accG[nf] = __builtin_amdgcn_mfma_f32_16x16x32_bf16(aRx[kc], bR, accG[nf], 0, 0, 0);
        }
    }
    __syncthreads();

    // ---- gather: 32 units x 8 lanes; unit handles exactly one row ----
    {
        const int r = tid >> 3, lane8 = tid & 7;
        const int j0 = offs[r], j1 = offs[r + 1];
        float ga[16];
#pragma unroll
        for (int q = 0; q < 16; ++q) ga[q] = 0.f;
        int j = j0;
        for (; j + 1 < j1; j += 2) {     // 2-way MLP
            int c0 = cols[j], c1 = cols[j + 1];
            uint4 v0 = *(const uint4*)&xq[(size_t)c0 * NF + lane8 * 16];
            uint4 v1 = *(const uint4*)&xq[(size_t)c1 * NF + lane8 * 16];
            DECADD(v0);
            DECADD(v1);
        }
        if (j < j1) {
            uint4 v0 = *(const uint4*)&xq[(size_t)cols[j] * NF + lane8 * 16];
            DECADD(v0);
        }
        float sc = 1.0f / (float)(j1 - j0 + 1);
        bf16x8 t0, t1;
#pragma unroll
        for (int q = 0; q < 8; ++q) t0[q] = (short)f32_to_bf16(ga[q] * sc);
#pragma unroll
        for (int q = 0; q < 8; ++q) t1[q] = (short)f32_to_bf16(ga[8 + q] * sc);
        uint base = (uint)r * 512 + (uint)lane8 * 32;
        uint x16 = (uint)(r & 7) << 4;
        *(bf16x8*)((char*)nl + (base ^ x16)) = t0;
        *(bf16x8*)((char*)nl + ((base + 16) ^ x16)) = t1;
    }
    __syncthreads();

    // ---- neigh-half GEMM: 4 waves, each 16 rows x 64 cols ----
#pragma unroll
    for (int kc = 4; kc < 8; ++kc) {
        uint boff = ((uint)lrow * 512 + (uint)((kc - 4) * 32 + lkb) * 2)
                    ^ ((uint)(lrow & 7) << 4);
        bf16x8 aR = *(const bf16x8*)((const char*)nl + boff);
        const ushort* wf = &Wfrag[(size_t)(kc * 8 + nquad * 4) * 512 + (size_t)lane * 8];
#pragma unroll
        for (int nf = 0; nf < 4; ++nf) {
            bf16x8 bR = *(const bf16x8*)(wf + (size_t)nf * 512);
            accG[nf] = __builtin_amdgcn_mfma_f32_16x16x32_bf16(aR, bR, accG[nf], 0, 0, 0);
        }
    }

    // ---- epilogue: ReLU + store (C layout: col=lane&15, row=(lane>>4)*4+reg) ----
    const int rb = mf * 16 + (lane >> 4) * 4;
#pragma unroll
    for (int j = 0; j < 4; ++j) {
        int row = b * RPB + rb + j;
        if (row < N) {
#pragma unroll
            for (int nf = 0; nf < 4; ++nf)
                out[(size_t)row * NF + (nquad * 4 + nf) * 16 + lm] = fmaxf(accG[nf][j], 0.f);
        }
    }
}

// ---------------- launcher ----------------
extern "C" void kernel_launch(void* const* d_in, const int* in_sizes, int n_in,
                              void* d_out, int out_size, void* d_ws, size_t ws_size,
                              hipStream_t stream) {
    const float* x    = (const float*)d_in[0];
    const int*   erow = (const int*)d_in[1];
    const int*   ecol = (const int*)d_in[2];
    const float* W    = (const float*)d_in[3];
    const int N = in_sizes[0] / NF;
    const int E = in_sizes[1];
    float* out = (float*)d_out;

    const int NB = (N + RPB - 1) / RPB;          // fine buckets (fused grid)
    const int NS = (N + SROWS - 1) / SROWS;      // super buckets
    const int total8 = N * NF / 8;
    const int CB = (total8 + PREP_THREADS * 4 - 1) / (PREP_THREADS * 4);
    const int BB = (E + CHUNK - 1) / CHUNK;

    // ws: xq[N*NF] | Wfrag[64*512*2] | bcur[NBMAX*4] | scur[256*4] |
    //     bbuf[NS*FPS*CAPB*4] | sbuf[NS*SCAP*4]   (~30.2 MB)
    char* ws = (char*)d_ws;
    uchar*  xq    = (uchar*)ws;
    ushort* Wfrag = (ushort*)(ws + (size_t)N * NF);
    int*    bcur  = (int*)((char*)Wfrag + 64 * 512 * 2);
    int*    scur  = bcur + NBMAX;
    uint*   bbuf  = (uint*)(scur + 256);
    uint*   sbuf  = bbuf + (size_t)NS * FPS * CAPB;

    hipMemsetAsync(scur, 0, (size_t)NS * sizeof(int), stream);
    prep_kernel<<<CB + 1 + BB, PREP_THREADS, 0, stream>>>(
        x, xq, total8, W, Wfrag, erow, ecol, scur, sbuf, E, NS, CB);
    binfine_kernel<<<NS, PREP_THREADS, 0, stream>>>(sbuf, scur, bbuf, bcur);
    fused_kernel<<<NB, 256, 0, stream>>>(x, xq, bcur, bbuf, Wfrag, out, N);
}